// Round 4
// baseline (4700.042 us; speedup 1.0000x reference)
//
#include <hip/hip_runtime.h>
#include <hip/hip_bf16.h>

// Problem constants
#define LL 6
#define DD 1024
#define HH 16
#define HDIM 64
#define FF 4096
#define BB 4
#define SS 2048
#define MM (BB * SS)  // 8192 rows

using f32x4 = __attribute__((ext_vector_type(4))) float;
using s16x8 = __attribute__((ext_vector_type(8))) short;
using s16x4 = __attribute__((ext_vector_type(4))) short;

static __device__ __forceinline__ short f2bf(float x) {
    unsigned u = __float_as_uint(x);
    u = u + 0x7fffu + ((u >> 16) & 1u);   // RNE, finite values only
    return (short)(u >> 16);
}

// ---------------------------------------------------------------------------
// init flags: done=0, depth=L
__global__ void init_k(int* flags) { flags[0] = 0; flags[1] = LL; }

__global__ void write_depth_k(float* out, const int* flags) { out[0] = (float)flags[1]; }

// ---------------------------------------------------------------------------
// fp32 [R][C] -> bf16 [C][R] transpose/convert (weights)
__global__ __launch_bounds__(256) void transpose_w(
    const float* __restrict__ in, short* __restrict__ out, int R, int C,
    const int* __restrict__ done)
{
    if (*done) return;
    __shared__ float t[32][33];
    const int tx = threadIdx.x & 31, ty = threadIdx.x >> 5;  // 32x8
    const int r0 = blockIdx.y * 32, c0 = blockIdx.x * 32;
#pragma unroll
    for (int j = 0; j < 32; j += 8)
        t[ty + j][tx] = in[(size_t)(r0 + ty + j) * C + c0 + tx];
    __syncthreads();
#pragma unroll
    for (int j = 0; j < 32; j += 8)
        out[(size_t)(c0 + ty + j) * R + r0 + tx] = f2bf(t[tx][ty + j]);
}

// ---------------------------------------------------------------------------
// LayerNorm over D=1024; fp32 in -> bf16 out. One block per row, 256 threads.
__global__ __launch_bounds__(256) void layernorm_k(
    const float* __restrict__ x, const float* __restrict__ g, const float* __restrict__ b,
    short* __restrict__ out, const int* __restrict__ done)
{
    if (*done) return;
    const int row = blockIdx.x, tid = threadIdx.x;
    const f32x4 v = *(const f32x4*)(x + (size_t)row * DD + tid * 4);
    float s  = v[0] + v[1] + v[2] + v[3];
    float sq = v[0]*v[0] + v[1]*v[1] + v[2]*v[2] + v[3]*v[3];
#pragma unroll
    for (int m = 1; m < 64; m <<= 1) { s += __shfl_xor(s, m, 64); sq += __shfl_xor(sq, m, 64); }
    __shared__ float red[8];
    if ((tid & 63) == 0) { red[tid >> 6] = s; red[4 + (tid >> 6)] = sq; }
    __syncthreads();
    s  = red[0] + red[1] + red[2] + red[3];
    sq = red[4] + red[5] + red[6] + red[7];
    const float mean = s * (1.f / DD);
    const float rstd = rsqrtf(sq * (1.f / DD) - mean * mean + 1e-5f);
    const f32x4 gg = *(const f32x4*)(g + tid * 4);
    const f32x4 bb = *(const f32x4*)(b + tid * 4);
    s16x4 o;
#pragma unroll
    for (int j = 0; j < 4; ++j) o[j] = f2bf((v[j] - mean) * rstd * gg[j] + bb[j]);
    *(s16x4*)(out + (size_t)row * DD + tid * 4) = o;
}

// ---------------------------------------------------------------------------
// GEMM: C[M][N] = A[M][K](bf16) @ Bt[N][K]^T(bf16) + bias
// EPI 0: bf16 out; 1: bf16 relu out; 2: fp32 in-place residual add (Cf += acc+bias)
// 128x128 tile, BK=32, 4 waves (2x2), 16x16x32 bf16 MFMA, 4x4 frags/wave.
template<int EPI>
__global__ __launch_bounds__(256) void gemm_bt(
    const short* __restrict__ A, const short* __restrict__ Bt,
    const float* __restrict__ bias,
    short* __restrict__ Cb, float* __restrict__ Cf,
    int M, int N, int K, const int* __restrict__ done)
{
    if (*done) return;
    __shared__ short As[128][40];   // pad to 80B rows: 2-way bank aliasing only
    __shared__ short Bs[128][40];
    const int tid = threadIdx.x;
    const int lane = tid & 63;
    const int wave = tid >> 6;
    const int wr = (wave >> 1) * 64, wc = (wave & 1) * 64;
    const int row0 = blockIdx.y * 128, col0 = blockIdx.x * 128;
    const int ra = tid >> 2, ka = (tid & 3) * 8;   // 512 16B-chunks / 256 thr = 2 each
    f32x4 acc[4][4] = {};
    for (int kt = 0; kt < K; kt += 32) {
        s16x8 a0 = *(const s16x8*)(A  + (size_t)(row0 + ra)      * K + kt + ka);
        s16x8 a1 = *(const s16x8*)(A  + (size_t)(row0 + ra + 64) * K + kt + ka);
        s16x8 b0 = *(const s16x8*)(Bt + (size_t)(col0 + ra)      * K + kt + ka);
        s16x8 b1 = *(const s16x8*)(Bt + (size_t)(col0 + ra + 64) * K + kt + ka);
        *(s16x8*)&As[ra][ka]      = a0;
        *(s16x8*)&As[ra + 64][ka] = a1;
        *(s16x8*)&Bs[ra][ka]      = b0;
        *(s16x8*)&Bs[ra + 64][ka] = b1;
        __syncthreads();
        s16x8 af[4], bfr[4];
#pragma unroll
        for (int m = 0; m < 4; ++m)
            af[m] = *(const s16x8*)&As[wr + m * 16 + (lane & 15)][(lane >> 4) * 8];
#pragma unroll
        for (int n = 0; n < 4; ++n)
            bfr[n] = *(const s16x8*)&Bs[wc + n * 16 + (lane & 15)][(lane >> 4) * 8];
#pragma unroll
        for (int m = 0; m < 4; ++m)
#pragma unroll
            for (int n = 0; n < 4; ++n)
                acc[m][n] = __builtin_amdgcn_mfma_f32_16x16x32_bf16(af[m], bfr[n], acc[m][n], 0, 0, 0);
        __syncthreads();
    }
#pragma unroll
    for (int m = 0; m < 4; ++m) {
        const int row = row0 + wr + m * 16 + (lane >> 4) * 4;
#pragma unroll
        for (int n = 0; n < 4; ++n) {
            const int col = col0 + wc + n * 16 + (lane & 15);
            const float bcol = bias[col];
#pragma unroll
            for (int i = 0; i < 4; ++i) {
                const float v = acc[m][n][i] + bcol;
                const size_t idx = (size_t)(row + i) * N + col;
                if (EPI == 0)      Cb[idx] = f2bf(v);
                else if (EPI == 1) Cb[idx] = f2bf(v > 0.f ? v : 0.f);
                else               Cf[idx] = Cf[idx] + v;
            }
        }
    }
}

// ---------------------------------------------------------------------------
// Flash attention, causal. Q/K/V/O: bf16 [B*S][D] row-major (head h at cols h*64..).
// Block: 256 thr = 4 waves; block handles (b,h) x 128 q-rows; wave = 32 q-rows.
// KV tile = 64. Online softmax in exp2 domain. scale = 1/8.
__global__ __launch_bounds__(256) void attn_k(
    const short* __restrict__ Q, const short* __restrict__ Kk, const short* __restrict__ V,
    short* __restrict__ O, const int* __restrict__ done)
{
    if (*done) return;
    __shared__ short Ks[64][72];        // K tile [kv][d], padded
    __shared__ short Vt[64][72];        // V tile transposed [d][kv], padded
    __shared__ short Pl[4][32][72];     // per-wave P [q][kv], padded
    const int tid = threadIdx.x, lane = tid & 63, wave = tid >> 6;
    const int bh = blockIdx.y, b = bh >> 4, h = bh & 15;
    const int qblock = blockIdx.x * 128;
    const int q0 = qblock + wave * 32;
    const size_t headoff = (size_t)b * SS * DD + h * HDIM;
    // Q fragments (held in regs the whole kernel)
    s16x8 qf[2][2];
#pragma unroll
    for (int m = 0; m < 2; ++m)
#pragma unroll
        for (int d0 = 0; d0 < 2; ++d0)
            qf[m][d0] = *(const s16x8*)(Q + headoff +
                (size_t)(q0 + m * 16 + (lane & 15)) * DD + d0 * 32 + (lane >> 4) * 8);
    f32x4 oacc[2][4] = {};
    float mrow[2][4], lrow[2][4];
#pragma unroll
    for (int m = 0; m < 2; ++m)
#pragma unroll
        for (int i = 0; i < 4; ++i) { mrow[m][i] = -__builtin_inff(); lrow[m][i] = 0.f; }
    const float sc = 0.125f * 1.44269504089f;  // scale * log2(e)
    const int r2 = tid >> 3, k2 = (tid & 7) * 8;   // K staging
    const int rv = tid >> 2, dq = (tid & 3) * 16;  // V staging
    const int jend = qblock + 64;                  // last tile base for this block
    for (int jb = 0; jb <= jend; jb += 64) {
        *(s16x8*)&Ks[r2][k2]      = *(const s16x8*)(Kk + headoff + (size_t)(jb + r2) * DD + k2);
        *(s16x8*)&Ks[r2 + 32][k2] = *(const s16x8*)(Kk + headoff + (size_t)(jb + r2 + 32) * DD + k2);
        {
            s16x8 v0 = *(const s16x8*)(V + headoff + (size_t)(jb + rv) * DD + dq);
            s16x8 v1 = *(const s16x8*)(V + headoff + (size_t)(jb + rv) * DD + dq + 8);
#pragma unroll
            for (int ii = 0; ii < 8; ++ii) Vt[dq + ii][rv] = v0[ii];
#pragma unroll
            for (int ii = 0; ii < 8; ++ii) Vt[dq + 8 + ii][rv] = v1[ii];
        }
        __syncthreads();
        if (jb <= q0 + 31) {
            const bool needmask = (jb + 63 > q0);
            f32x4 sf[2][4] = {};
#pragma unroll
            for (int n = 0; n < 4; ++n)
#pragma unroll
                for (int d0 = 0; d0 < 2; ++d0) {
                    const s16x8 kf = *(const s16x8*)&Ks[n * 16 + (lane & 15)][d0 * 32 + (lane >> 4) * 8];
#pragma unroll
                    for (int m = 0; m < 2; ++m)
                        sf[m][n] = __builtin_amdgcn_mfma_f32_16x16x32_bf16(qf[m][d0], kf, sf[m][n], 0, 0, 0);
                }
#pragma unroll
            for (int m = 0; m < 2; ++m) {
                float tmax[4] = {-__builtin_inff(), -__builtin_inff(), -__builtin_inff(), -__builtin_inff()};
#pragma unroll
                for (int n = 0; n < 4; ++n)
#pragma unroll
                    for (int i = 0; i < 4; ++i) {
                        float s = sf[m][n][i] * sc;
                        if (needmask) {
                            const int kv = jb + n * 16 + (lane & 15);
                            const int qr = q0 + m * 16 + (lane >> 4) * 4 + i;
                            if (kv > qr) s = -1e30f;
                        }
                        sf[m][n][i] = s;
                        tmax[i] = fmaxf(tmax[i], s);
                    }
#pragma unroll
                for (int i = 0; i < 4; ++i) {
#pragma unroll
                    for (int mk = 1; mk < 16; mk <<= 1)
                        tmax[i] = fmaxf(tmax[i], __shfl_xor(tmax[i], mk, 64));
                    const float mnew = fmaxf(mrow[m][i], tmax[i]);
                    const float alpha = exp2f(mrow[m][i] - mnew);
                    mrow[m][i] = mnew;
                    lrow[m][i] *= alpha;
#pragma unroll
                    for (int df = 0; df < 4; ++df) oacc[m][df][i] *= alpha;
                }
                float psum[4] = {0.f, 0.f, 0.f, 0.f};
#pragma unroll
                for (int n = 0; n < 4; ++n)
#pragma unroll
                    for (int i = 0; i < 4; ++i) {
                        const float p = exp2f(sf[m][n][i] - mrow[m][i]);
                        psum[i] += p;
                        Pl[wave][m * 16 + (lane >> 4) * 4 + i][n * 16 + (lane & 15)] = f2bf(p);
                    }
#pragma unroll
                for (int i = 0; i < 4; ++i) {
#pragma unroll
                    for (int mk = 1; mk < 16; mk <<= 1) psum[i] += __shfl_xor(psum[i], mk, 64);
                    lrow[m][i] += psum[i];
                }
            }
            // PV (wave-private Pl: same-wave ds write->read, compiler inserts waits)
#pragma unroll
            for (int ks = 0; ks < 2; ++ks) {
                s16x8 pa[2];
#pragma unroll
                for (int m = 0; m < 2; ++m)
                    pa[m] = *(const s16x8*)&Pl[wave][m * 16 + (lane & 15)][ks * 32 + (lane >> 4) * 8];
#pragma unroll
                for (int df = 0; df < 4; ++df) {
                    const s16x8 vbf = *(const s16x8*)&Vt[df * 16 + (lane & 15)][ks * 32 + (lane >> 4) * 8];
#pragma unroll
                    for (int m = 0; m < 2; ++m)
                        oacc[m][df] = __builtin_amdgcn_mfma_f32_16x16x32_bf16(pa[m], vbf, oacc[m][df], 0, 0, 0);
                }
            }
        }
        __syncthreads();
    }
#pragma unroll
    for (int m = 0; m < 2; ++m)
#pragma unroll
        for (int i = 0; i < 4; ++i) {
            const int qr = q0 + m * 16 + (lane >> 4) * 4 + i;
            const float inv = 1.f / lrow[m][i];
#pragma unroll
            for (int df = 0; df < 4; ++df)
                O[headoff + (size_t)qr * DD + df * 16 + (lane & 15)] = f2bf(oacc[m][df][i] * inv);
        }
}

// ---------------------------------------------------------------------------
// Confidence path: column sums of x over seq, then probe + sigmoid + mean.
__global__ void zero_colsum(float* cs, const int* done) {
    if (*done) return;
    cs[blockIdx.x * 256 + threadIdx.x] = 0.f;
}

__global__ __launch_bounds__(256) void colsum_k(
    const float* __restrict__ x, float* __restrict__ cs, const int* __restrict__ done)
{
    if (*done) return;
    const int d = (blockIdx.x & 3) * 256 + threadIdx.x;
    const int b = blockIdx.x >> 2;
    const int s0 = blockIdx.y * 128;
    float s = 0.f;
    for (int i = 0; i < 128; ++i) s += x[(size_t)(b * SS + s0 + i) * DD + d];
    atomicAdd(&cs[b * DD + d], s);
}

__global__ __launch_bounds__(256) void conf_k(
    const float* __restrict__ colsum, const float* __restrict__ cW, const float* __restrict__ cb,
    int layer, int* __restrict__ flags)
{
    if (flags[0]) return;
    const int tid = threadIdx.x;
    __shared__ float red[4][4];
    float dot[4];
#pragma unroll
    for (int b = 0; b < 4; ++b) {
        float p = 0.f;
        for (int d = tid; d < DD; d += 256) p += colsum[b * DD + d] * cW[d];
#pragma unroll
        for (int m = 1; m < 64; m <<= 1) p += __shfl_xor(p, m, 64);
        dot[b] = p;
    }
    if ((tid & 63) == 0) {
#pragma unroll
        for (int b = 0; b < 4; ++b) red[b][tid >> 6] = dot[b];
    }
    __syncthreads();
    if (tid == 0) {
        float conf = 0.f;
#pragma unroll
        for (int b = 0; b < 4; ++b) {
            const float db = (red[b][0] + red[b][1] + red[b][2] + red[b][3]) * (1.f / SS) + cb[0];
            conf += 1.f / (1.f + expf(-db));
        }
        conf *= 0.25f;
        if (layer >= 1 && conf > 0.93f) { flags[0] = 1; flags[1] = layer + 1; }
    }
}

// ---------------------------------------------------------------------------
extern "C" void kernel_launch(void* const* d_in, const int* in_sizes, int n_in,
                              void* d_out, int out_size, void* d_ws, size_t ws_size,
                              hipStream_t stream)
{
    const float* x_in = (const float*)d_in[0];
    const float* Wq  = (const float*)d_in[1];
    const float* bq  = (const float*)d_in[2];
    const float* Wk  = (const float*)d_in[3];
    const float* bk  = (const float*)d_in[4];
    const float* Wv  = (const float*)d_in[5];
    const float* bv  = (const float*)d_in[6];
    const float* Wo  = (const float*)d_in[7];
    const float* bo  = (const float*)d_in[8];
    const float* W1  = (const float*)d_in[9];
    const float* b1  = (const float*)d_in[10];
    const float* W2  = (const float*)d_in[11];
    const float* b2  = (const float*)d_in[12];
    const float* g1  = (const float*)d_in[13];
    const float* be1 = (const float*)d_in[14];
    const float* g2  = (const float*)d_in[15];
    const float* be2 = (const float*)d_in[16];
    const float* cW  = (const float*)d_in[17];
    const float* cb  = (const float*)d_in[18];

    char* ws = (char*)d_ws;
    size_t off = 0;
    auto alloc = [&](size_t bytes) -> char* {
        char* p = ws + off;
        off = (off + bytes + 255) & ~(size_t)255;
        return p;
    };
    int*   flags  = (int*)  alloc(256);
    float* colsum = (float*)alloc((size_t)BB * DD * 4);
    short* xn     = (short*)alloc((size_t)MM * DD * 2);
    short* qb     = (short*)alloc((size_t)MM * DD * 2);
    short* kb     = (short*)alloc((size_t)MM * DD * 2);
    short* vb     = (short*)alloc((size_t)MM * DD * 2);
    short* obuf   = (short*)alloc((size_t)MM * DD * 2);
    short* hb     = qb;  // FFN hidden [MM][FF] bf16 overlaps q/k/v/o (dead by then)
    short* wtq    = (short*)alloc((size_t)DD * DD * 2);
    short* wtk    = (short*)alloc((size_t)DD * DD * 2);
    short* wtv    = (short*)alloc((size_t)DD * DD * 2);
    short* wto    = (short*)alloc((size_t)DD * DD * 2);
    short* wt1    = (short*)alloc((size_t)DD * FF * 2);
    short* wt2    = (short*)alloc((size_t)DD * FF * 2);
    (void)ws_size; (void)in_sizes; (void)n_in; (void)out_size;

    // fp32 residual stream lives directly in d_out (out layout: [MM*DD floats][depth])
    float* x = (float*)d_out;

    hipMemcpyAsync(x, x_in, (size_t)MM * DD * 4, hipMemcpyDeviceToDevice, stream);
    init_k<<<1, 1, 0, stream>>>(flags);
    const int* done = flags;

    for (int l = 0; l < LL; ++l) {
        const size_t wdd = (size_t)l * DD * DD;
        const size_t wdf = (size_t)l * DD * FF;
        transpose_w<<<dim3(32, 32), 256, 0, stream>>>(Wq + wdd, wtq, DD, DD, done);
        transpose_w<<<dim3(32, 32), 256, 0, stream>>>(Wk + wdd, wtk, DD, DD, done);
        transpose_w<<<dim3(32, 32), 256, 0, stream>>>(Wv + wdd, wtv, DD, DD, done);
        transpose_w<<<dim3(32, 32), 256, 0, stream>>>(Wo + wdd, wto, DD, DD, done);
        transpose_w<<<dim3(128, 32), 256, 0, stream>>>(W1 + wdf, wt1, DD, FF, done);
        transpose_w<<<dim3(32, 128), 256, 0, stream>>>(W2 + wdf, wt2, FF, DD, done);

        layernorm_k<<<MM, 256, 0, stream>>>(x, g1 + l * DD, be1 + l * DD, xn, done);
        gemm_bt<0><<<dim3(DD / 128, MM / 128), 256, 0, stream>>>(xn, wtq, bq + l * DD, qb, nullptr, MM, DD, DD, done);
        gemm_bt<0><<<dim3(DD / 128, MM / 128), 256, 0, stream>>>(xn, wtk, bk + l * DD, kb, nullptr, MM, DD, DD, done);
        gemm_bt<0><<<dim3(DD / 128, MM / 128), 256, 0, stream>>>(xn, wtv, bv + l * DD, vb, nullptr, MM, DD, DD, done);
        attn_k<<<dim3(SS / 128, BB * HH), 256, 0, stream>>>(qb, kb, vb, obuf, done);
        gemm_bt<2><<<dim3(DD / 128, MM / 128), 256, 0, stream>>>(obuf, wto, bo + l * DD, nullptr, x, MM, DD, DD, done);
        layernorm_k<<<MM, 256, 0, stream>>>(x, g2 + l * DD, be2 + l * DD, xn, done);
        gemm_bt<1><<<dim3(FF / 128, MM / 128), 256, 0, stream>>>(xn, wt1, b1 + (size_t)l * FF, hb, nullptr, MM, FF, DD, done);
        gemm_bt<2><<<dim3(DD / 128, MM / 128), 256, 0, stream>>>(hb, wt2, b2 + l * DD, nullptr, x, MM, DD, FF, done);

        zero_colsum<<<16, 256, 0, stream>>>(colsum, done);
        colsum_k<<<dim3(16, 16), 256, 0, stream>>>(x, colsum, done);
        conf_k<<<1, 256, 0, stream>>>(colsum, cW + l * DD, cb + l, l, flags);
    }

    write_depth_k<<<1, 1, 0, stream>>>((float*)d_out + (size_t)MM * DD, flags);
}

// Round 6
// 3612.383 us; speedup vs baseline: 1.3011x; 1.3011x over previous
//
#include <hip/hip_runtime.h>
#include <hip/hip_bf16.h>

// Problem constants
#define LL 6
#define DD 1024
#define HH 16
#define HDIM 64
#define FF 4096
#define BB 4
#define SS 2048
#define MM (BB * SS)  // 8192 rows

using f32x4 = __attribute__((ext_vector_type(4))) float;
using s16x8 = __attribute__((ext_vector_type(8))) short;
using s16x4 = __attribute__((ext_vector_type(4))) short;

static __device__ __forceinline__ short f2bf(float x) {
    unsigned u = __float_as_uint(x);
    u = u + 0x7fffu + ((u >> 16) & 1u);   // RNE, finite values only
    return (short)(u >> 16);
}

// async global->LDS, 16B per lane; lds dst must be wave-uniform base (+lane*16 implicit)
static __device__ __forceinline__ void gl_lds16(const short* g, short* l) {
    __builtin_amdgcn_global_load_lds(
        (const __attribute__((address_space(1))) void*)g,
        (__attribute__((address_space(3))) void*)l, 16, 0, 0);
}

// ---------------------------------------------------------------------------
__global__ void init_k(int* flags) { flags[0] = 0; flags[1] = LL; }

__global__ void write_depth_k(float* out, const int* flags) { out[0] = (float)flags[1]; }

// ---------------------------------------------------------------------------
// fp32 [R][C] -> bf16 [C][R] transpose/convert (weights)
__global__ __launch_bounds__(256) void transpose_w(
    const float* __restrict__ in, short* __restrict__ out, int R, int C,
    const int* __restrict__ done)
{
    if (*done) return;
    __shared__ float t[32][33];
    const int tx = threadIdx.x & 31, ty = threadIdx.x >> 5;  // 32x8
    const int r0 = blockIdx.y * 32, c0 = blockIdx.x * 32;
#pragma unroll
    for (int j = 0; j < 32; j += 8)
        t[ty + j][tx] = in[(size_t)(r0 + ty + j) * C + c0 + tx];
    __syncthreads();
#pragma unroll
    for (int j = 0; j < 32; j += 8)
        out[(size_t)(c0 + ty + j) * R + r0 + tx] = f2bf(t[tx][ty + j]);
}

// ---------------------------------------------------------------------------
// LayerNorm over D=1024; fp32 in -> bf16 out. One block per row, 256 threads.
__global__ __launch_bounds__(256) void layernorm_k(
    const float* __restrict__ x, const float* __restrict__ g, const float* __restrict__ b,
    short* __restrict__ out, const int* __restrict__ done)
{
    if (*done) return;
    const int row = blockIdx.x, tid = threadIdx.x;
    const f32x4 v = *(const f32x4*)(x + (size_t)row * DD + tid * 4);
    float s  = v[0] + v[1] + v[2] + v[3];
    float sq = v[0]*v[0] + v[1]*v[1] + v[2]*v[2] + v[3]*v[3];
#pragma unroll
    for (int m = 1; m < 64; m <<= 1) { s += __shfl_xor(s, m, 64); sq += __shfl_xor(sq, m, 64); }
    __shared__ float red[8];
    if ((tid & 63) == 0) { red[tid >> 6] = s; red[4 + (tid >> 6)] = sq; }
    __syncthreads();
    s  = red[0] + red[1] + red[2] + red[3];
    sq = red[4] + red[5] + red[6] + red[7];
    const float mean = s * (1.f / DD);
    const float rstd = rsqrtf(sq * (1.f / DD) - mean * mean + 1e-5f);
    const f32x4 gg = *(const f32x4*)(g + tid * 4);
    const f32x4 bb = *(const f32x4*)(b + tid * 4);
    s16x4 o;
#pragma unroll
    for (int j = 0; j < 4; ++j) o[j] = f2bf((v[j] - mean) * rstd * gg[j] + bb[j]);
    *(s16x4*)(out + (size_t)row * DD + tid * 4) = o;
}

// ---------------------------------------------------------------------------
// GEMM: C[M][N] = A[M][K](bf16) @ Bt[N][K]^T(bf16) + bias
// EPI 0: bf16 out; 1: bf16 relu out; 2: fp32 in-place residual add;
// EPI 3: bf16 transposed head-major out (V^T: [bh][64 d][2048 s]) for attention.
// 128x128 tile, BK=32, 4 waves (2x2), 16x16x32 bf16 MFMA, 4x4 frags/wave.
// Staging via global_load_lds width=16 into LINEAR [128][32] LDS (m97 structure).
template<int EPI>
__global__ __launch_bounds__(256) void gemm_bt(
    const short* __restrict__ A, const short* __restrict__ Bt,
    const float* __restrict__ bias,
    short* __restrict__ Cb, float* __restrict__ Cf,
    int M, int N, int K, const int* __restrict__ done)
{
    if (*done) return;
    __shared__ __align__(16) short As[128 * 32];   // linear, row-major [128][32]
    __shared__ __align__(16) short Bs[128 * 32];
    const int tid = threadIdx.x;
    const int lane = tid & 63;
    const int wave = tid >> 6;
    const int wr = (wave >> 1) * 64, wc = (wave & 1) * 64;
    const int row0 = blockIdx.y * 128, col0 = blockIdx.x * 128;
    // chunk c in [0,512): row=c>>2, k-chunk=(c&3)*8 shorts. 2 chunks/thread.
    const int r0c = tid >> 2,        k0c = (tid & 3) * 8;
    const int r1c = (256 + tid) >> 2, k1c = (tid & 3) * 8;  // (256+tid)&3 == tid&3
    short* dstA0 = As + (size_t)(wave * 64) * 8;
    short* dstA1 = As + (size_t)(256 + wave * 64) * 8;
    short* dstB0 = Bs + (size_t)(wave * 64) * 8;
    short* dstB1 = Bs + (size_t)(256 + wave * 64) * 8;
    f32x4 acc[4][4] = {};
    for (int kt = 0; kt < K; kt += 32) {
        gl_lds16(A  + (size_t)(row0 + r0c) * K + kt + k0c, dstA0);
        gl_lds16(A  + (size_t)(row0 + r1c) * K + kt + k1c, dstA1);
        gl_lds16(Bt + (size_t)(col0 + r0c) * K + kt + k0c, dstB0);
        gl_lds16(Bt + (size_t)(col0 + r1c) * K + kt + k1c, dstB1);
        __syncthreads();   // drains vmcnt (compiler emits s_waitcnt vmcnt(0) before barrier)
        s16x8 af[4], bfr[4];
#pragma unroll
        for (int m = 0; m < 4; ++m)
            af[m] = *(const s16x8*)&As[(wr + m * 16 + (lane & 15)) * 32 + (lane >> 4) * 8];
#pragma unroll
        for (int n = 0; n < 4; ++n)
            bfr[n] = *(const s16x8*)&Bs[(wc + n * 16 + (lane & 15)) * 32 + (lane >> 4) * 8];
#pragma unroll
        for (int m = 0; m < 4; ++m)
#pragma unroll
            for (int n = 0; n < 4; ++n)
                acc[m][n] = __builtin_amdgcn_mfma_f32_16x16x32_bf16(af[m], bfr[n], acc[m][n], 0, 0, 0);
        __syncthreads();
    }
#pragma unroll
    for (int m = 0; m < 4; ++m) {
        const int row = row0 + wr + m * 16 + (lane >> 4) * 4;
#pragma unroll
        for (int n = 0; n < 4; ++n) {
            const int col = col0 + wc + n * 16 + (lane & 15);
            const float bcol = bias[col];
            if (EPI == 3) {
                // transposed bf16: Cb = vt[(bh*64+d)*2048 + s], 4 consecutive s per store
                const int bh = (row >> 11) * HH + (col >> 6);
                const int d = col & 63, s = row & 2047;
                s16x4 o;
#pragma unroll
                for (int i = 0; i < 4; ++i) o[i] = f2bf(acc[m][n][i] + bcol);
                *(s16x4*)(Cb + ((size_t)bh * 64 + d) * SS + s) = o;
            } else {
#pragma unroll
                for (int i = 0; i < 4; ++i) {
                    const float v = acc[m][n][i] + bcol;
                    const size_t idx = (size_t)(row + i) * N + col;
                    if (EPI == 0)      Cb[idx] = f2bf(v);
                    else if (EPI == 1) Cb[idx] = f2bf(v > 0.f ? v : 0.f);
                    else               Cf[idx] = Cf[idx] + v;
                }
            }
        }
    }
}

// ---------------------------------------------------------------------------
// Flash attention, causal. Q/K/O: bf16 [B*S][D] row-major; V pre-transposed
// vt[bh][64 d][2048 s]. Block: 4 waves; fold-paired q-tiles {t, 15-t} for
// uniform causal work (34 KV-tile iterations per block). Wave = 32 q-rows.
__global__ __launch_bounds__(256) void attn_k(
    const short* __restrict__ Q, const short* __restrict__ Kk, const short* __restrict__ Vt_g,
    short* __restrict__ O, const int* __restrict__ done)
{
    if (*done) return;
    __shared__ __align__(16) short Ks[64][72];    // K tile [kv][d], padded
    __shared__ __align__(16) short Vs[64][72];    // V^T tile [d][kv], padded
    __shared__ __align__(16) short Pl[4][32][72]; // per-wave P [q][kv], padded
    const int tid = threadIdx.x, lane = tid & 63, wave = tid >> 6;
    const int bh = blockIdx.y, b = bh >> 4, h = bh & 15;
    const size_t headoff = (size_t)b * SS * DD + h * HDIM;
    const size_t vhead = (size_t)bh * 64 * SS;
    const float sc = 0.125f * 1.44269504089f;  // scale * log2(e)
    const int r2 = tid >> 3, k2 = (tid & 7) * 8;   // K staging rows 0..31 (+32)
    const int rvA = tid >> 3, cvA = (tid & 7) * 8; // V^T staging rows 0..31
    const int rvB = 32 + rvA;                      // rows 32..63
    for (int half = 0; half < 2; ++half) {
        const int qtile = half ? (15 - blockIdx.x) : blockIdx.x;
        const int qblock = qtile * 128;
        const int q0 = qblock + wave * 32;
        // Q fragments (held in regs for this half)
        s16x8 qf[2][2];
#pragma unroll
        for (int m = 0; m < 2; ++m)
#pragma unroll
            for (int d0 = 0; d0 < 2; ++d0)
                qf[m][d0] = *(const s16x8*)(Q + headoff +
                    (size_t)(q0 + m * 16 + (lane & 15)) * DD + d0 * 32 + (lane >> 4) * 8);
        f32x4 oacc[2][4] = {};
        float mrow[2][4], lrow[2][4];
#pragma unroll
        for (int m = 0; m < 2; ++m)
#pragma unroll
            for (int i = 0; i < 4; ++i) { mrow[m][i] = -__builtin_inff(); lrow[m][i] = 0.f; }
        const int jend = qblock + 64;
        for (int jb = 0; jb <= jend; jb += 64) {
            *(s16x8*)&Ks[r2][k2]      = *(const s16x8*)(Kk + headoff + (size_t)(jb + r2) * DD + k2);
            *(s16x8*)&Ks[r2 + 32][k2] = *(const s16x8*)(Kk + headoff + (size_t)(jb + r2 + 32) * DD + k2);
            *(s16x8*)&Vs[rvA][cvA]    = *(const s16x8*)(Vt_g + vhead + (size_t)rvA * SS + jb + cvA);
            *(s16x8*)&Vs[rvB][cvA]    = *(const s16x8*)(Vt_g + vhead + (size_t)rvB * SS + jb + cvA);
            __syncthreads();
            if (jb <= q0 + 31) {
                const bool needmask = (jb + 63 > q0);
                f32x4 sf[2][4] = {};
#pragma unroll
                for (int n = 0; n < 4; ++n)
#pragma unroll
                    for (int d0 = 0; d0 < 2; ++d0) {
                        const s16x8 kf = *(const s16x8*)&Ks[n * 16 + (lane & 15)][d0 * 32 + (lane >> 4) * 8];
#pragma unroll
                        for (int m = 0; m < 2; ++m)
                            sf[m][n] = __builtin_amdgcn_mfma_f32_16x16x32_bf16(qf[m][d0], kf, sf[m][n], 0, 0, 0);
                    }
#pragma unroll
                for (int m = 0; m < 2; ++m) {
                    float tmax[4] = {-__builtin_inff(), -__builtin_inff(), -__builtin_inff(), -__builtin_inff()};
#pragma unroll
                    for (int n = 0; n < 4; ++n)
#pragma unroll
                        for (int i = 0; i < 4; ++i) {
                            float s = sf[m][n][i] * sc;
                            if (needmask) {
                                const int kv = jb + n * 16 + (lane & 15);
                                const int qr = q0 + m * 16 + (lane >> 4) * 4 + i;
                                if (kv > qr) s = -1e30f;
                            }
                            sf[m][n][i] = s;
                            tmax[i] = fmaxf(tmax[i], s);
                        }
#pragma unroll
                    for (int i = 0; i < 4; ++i) {
#pragma unroll
                        for (int mk = 1; mk < 16; mk <<= 1)
                            tmax[i] = fmaxf(tmax[i], __shfl_xor(tmax[i], mk, 64));
                        const float mnew = fmaxf(mrow[m][i], tmax[i]);
                        const float alpha = exp2f(mrow[m][i] - mnew);
                        mrow[m][i] = mnew;
                        lrow[m][i] *= alpha;
#pragma unroll
                        for (int df = 0; df < 4; ++df) oacc[m][df][i] *= alpha;
                    }
                    float psum[4] = {0.f, 0.f, 0.f, 0.f};
#pragma unroll
                    for (int n = 0; n < 4; ++n)
#pragma unroll
                        for (int i = 0; i < 4; ++i) {
                            const float p = exp2f(sf[m][n][i] - mrow[m][i]);
                            psum[i] += p;
                            Pl[wave][m * 16 + (lane >> 4) * 4 + i][n * 16 + (lane & 15)] = f2bf(p);
                        }
#pragma unroll
                    for (int i = 0; i < 4; ++i) {
#pragma unroll
                        for (int mk = 1; mk < 16; mk <<= 1) psum[i] += __shfl_xor(psum[i], mk, 64);
                        lrow[m][i] += psum[i];
                    }
                }
                // PV (wave-private Pl)
#pragma unroll
                for (int ks = 0; ks < 2; ++ks) {
                    s16x8 pa[2];
#pragma unroll
                    for (int m = 0; m < 2; ++m)
                        pa[m] = *(const s16x8*)&Pl[wave][m * 16 + (lane & 15)][ks * 32 + (lane >> 4) * 8];
#pragma unroll
                    for (int df = 0; df < 4; ++df) {
                        const s16x8 vbf = *(const s16x8*)&Vs[df * 16 + (lane & 15)][ks * 32 + (lane >> 4) * 8];
#pragma unroll
                        for (int m = 0; m < 2; ++m)
                            oacc[m][df] = __builtin_amdgcn_mfma_f32_16x16x32_bf16(pa[m], vbf, oacc[m][df], 0, 0, 0);
                    }
                }
            }
            __syncthreads();
        }
#pragma unroll
        for (int m = 0; m < 2; ++m)
#pragma unroll
            for (int i = 0; i < 4; ++i) {
                const int qr = q0 + m * 16 + (lane >> 4) * 4 + i;
                const float inv = 1.f / lrow[m][i];
#pragma unroll
                for (int df = 0; df < 4; ++df)
                    O[headoff + (size_t)qr * DD + df * 16 + (lane & 15)] = f2bf(oacc[m][df][i] * inv);
            }
    }
}

// ---------------------------------------------------------------------------
// Confidence path: column sums of x over seq, then probe + sigmoid + mean.
__global__ void zero_colsum(float* cs, const int* done) {
    if (*done) return;
    cs[blockIdx.x * 256 + threadIdx.x] = 0.f;
}

__global__ __launch_bounds__(256) void colsum_k(
    const float* __restrict__ x, float* __restrict__ cs, const int* __restrict__ done)
{
    if (*done) return;
    const int d = (blockIdx.x & 3) * 256 + threadIdx.x;
    const int b = blockIdx.x >> 2;
    const int s0 = blockIdx.y * 128;
    float s = 0.f;
    for (int i = 0; i < 128; ++i) s += x[(size_t)(b * SS + s0 + i) * DD + d];
    atomicAdd(&cs[b * DD + d], s);
}

__global__ __launch_bounds__(256) void conf_k(
    const float* __restrict__ colsum, const float* __restrict__ cW, const float* __restrict__ cb,
    int layer, int* __restrict__ flags)
{
    if (flags[0]) return;
    const int tid = threadIdx.x;
    __shared__ float red[4][4];
    float dot[4];
#pragma unroll
    for (int b = 0; b < 4; ++b) {
        float p = 0.f;
        for (int d = tid; d < DD; d += 256) p += colsum[b * DD + d] * cW[d];
#pragma unroll
        for (int m = 1; m < 64; m <<= 1) p += __shfl_xor(p, m, 64);
        dot[b] = p;
    }
    if ((tid & 63) == 0) {
#pragma unroll
        for (int b = 0; b < 4; ++b) red[b][tid >> 6] = dot[b];
    }
    __syncthreads();
    if (tid == 0) {
        float conf = 0.f;
#pragma unroll
        for (int b = 0; b < 4; ++b) {
            const float db = (red[b][0] + red[b][1] + red[b][2] + red[b][3]) * (1.f / SS) + cb[0];
            conf += 1.f / (1.f + expf(-db));
        }
        conf *= 0.25f;
        if (layer >= 1 && conf > 0.93f) { flags[0] = 1; flags[1] = layer + 1; }
    }
}

// ---------------------------------------------------------------------------
extern "C" void kernel_launch(void* const* d_in, const int* in_sizes, int n_in,
                              void* d_out, int out_size, void* d_ws, size_t ws_size,
                              hipStream_t stream)
{
    const float* x_in = (const float*)d_in[0];
    const float* Wq  = (const float*)d_in[1];
    const float* bq  = (const float*)d_in[2];
    const float* Wk  = (const float*)d_in[3];
    const float* bk  = (const float*)d_in[4];
    const float* Wv  = (const float*)d_in[5];
    const float* bv  = (const float*)d_in[6];
    const float* Wo  = (const float*)d_in[7];
    const float* bo  = (const float*)d_in[8];
    const float* W1  = (const float*)d_in[9];
    const float* b1  = (const float*)d_in[10];
    const float* W2  = (const float*)d_in[11];
    const float* b2  = (const float*)d_in[12];
    const float* g1  = (const float*)d_in[13];
    const float* be1 = (const float*)d_in[14];
    const float* g2  = (const float*)d_in[15];
    const float* be2 = (const float*)d_in[16];
    const float* cW  = (const float*)d_in[17];
    const float* cb  = (const float*)d_in[18];

    char* ws = (char*)d_ws;
    size_t off = 0;
    auto alloc = [&](size_t bytes) -> char* {
        char* p = ws + off;
        off = (off + bytes + 255) & ~(size_t)255;
        return p;
    };
    int*   flags  = (int*)  alloc(256);
    float* colsum = (float*)alloc((size_t)BB * DD * 4);
    short* xn     = (short*)alloc((size_t)MM * DD * 2);
    short* qb     = (short*)alloc((size_t)MM * DD * 2);
    short* kb     = (short*)alloc((size_t)MM * DD * 2);
    short* vt     = (short*)alloc((size_t)MM * DD * 2);  // V^T [bh][64][2048]
    short* obuf   = (short*)alloc((size_t)MM * DD * 2);
    short* hb     = qb;  // FFN hidden [MM][FF] bf16 overlaps q/k/vt/o (dead by then)
    short* wtq    = (short*)alloc((size_t)DD * DD * 2);
    short* wtk    = (short*)alloc((size_t)DD * DD * 2);
    short* wtv    = (short*)alloc((size_t)DD * DD * 2);
    short* wto    = (short*)alloc((size_t)DD * DD * 2);
    short* wt1    = (short*)alloc((size_t)DD * FF * 2);
    short* wt2    = (short*)alloc((size_t)DD * FF * 2);
    (void)ws_size; (void)in_sizes; (void)n_in; (void)out_size;

    // fp32 residual stream lives directly in d_out (out layout: [MM*DD floats][depth])
    float* x = (float*)d_out;

    hipMemcpyAsync(x, x_in, (size_t)MM * DD * 4, hipMemcpyDeviceToDevice, stream);
    init_k<<<1, 1, 0, stream>>>(flags);
    const int* done = flags;

    for (int l = 0; l < LL; ++l) {
        const size_t wdd = (size_t)l * DD * DD;
        const size_t wdf = (size_t)l * DD * FF;
        transpose_w<<<dim3(32, 32), 256, 0, stream>>>(Wq + wdd, wtq, DD, DD, done);
        transpose_w<<<dim3(32, 32), 256, 0, stream>>>(Wk + wdd, wtk, DD, DD, done);
        transpose_w<<<dim3(32, 32), 256, 0, stream>>>(Wv + wdd, wtv, DD, DD, done);
        transpose_w<<<dim3(32, 32), 256, 0, stream>>>(Wo + wdd, wto, DD, DD, done);
        transpose_w<<<dim3(128, 32), 256, 0, stream>>>(W1 + wdf, wt1, DD, FF, done);
        transpose_w<<<dim3(32, 128), 256, 0, stream>>>(W2 + wdf, wt2, FF, DD, done);

        layernorm_k<<<MM, 256, 0, stream>>>(x, g1 + l * DD, be1 + l * DD, xn, done);
        gemm_bt<0><<<dim3(DD / 128, MM / 128), 256, 0, stream>>>(xn, wtq, bq + l * DD, qb, nullptr, MM, DD, DD, done);
        gemm_bt<0><<<dim3(DD / 128, MM / 128), 256, 0, stream>>>(xn, wtk, bk + l * DD, kb, nullptr, MM, DD, DD, done);
        gemm_bt<3><<<dim3(DD / 128, MM / 128), 256, 0, stream>>>(xn, wtv, bv + l * DD, vt, nullptr, MM, DD, DD, done);
        attn_k<<<dim3(8, BB * HH), 256, 0, stream>>>(qb, kb, vt, obuf, done);
        gemm_bt<2><<<dim3(DD / 128, MM / 128), 256, 0, stream>>>(obuf, wto, bo + l * DD, nullptr, x, MM, DD, DD, done);
        layernorm_k<<<MM, 256, 0, stream>>>(x, g2 + l * DD, be2 + l * DD, xn, done);
        gemm_bt<1><<<dim3(FF / 128, MM / 128), 256, 0, stream>>>(xn, wt1, b1 + (size_t)l * FF, hb, nullptr, MM, FF, DD, done);
        gemm_bt<2><<<dim3(DD / 128, MM / 128), 256, 0, stream>>>(hb, wt2, b2 + l * DD, nullptr, x, MM, DD, FF, done);

        zero_colsum<<<16, 256, 0, stream>>>(colsum, done);
        colsum_k<<<dim3(16, 16), 256, 0, stream>>>(x, colsum, done);
        conf_k<<<1, 256, 0, stream>>>(colsum, cW + l * DD, cb + l, l, flags);
    }

    write_depth_k<<<1, 1, 0, stream>>>((float*)d_out + (size_t)MM * DD, flags);
}

// Round 7
// 3255.180 us; speedup vs baseline: 1.4439x; 1.1097x over previous
//
#include <hip/hip_runtime.h>
#include <hip/hip_bf16.h>

// Problem constants
#define LL 6
#define DD 1024
#define HH 16
#define HDIM 64
#define FF 4096
#define BB 4
#define SS 2048
#define MM (BB * SS)  // 8192 rows

using f32x4 = __attribute__((ext_vector_type(4))) float;
using s16x8 = __attribute__((ext_vector_type(8))) short;
using s16x4 = __attribute__((ext_vector_type(4))) short;

static __device__ __forceinline__ short f2bf(float x) {
    unsigned u = __float_as_uint(x);
    u = u + 0x7fffu + ((u >> 16) & 1u);   // RNE, finite values only
    return (short)(u >> 16);
}

// async global->LDS, 16B per lane; lds dst must be wave-uniform base (+lane*16 implicit)
static __device__ __forceinline__ void gl_lds16(const short* g, short* l) {
    __builtin_amdgcn_global_load_lds(
        (const __attribute__((address_space(1))) void*)g,
        (__attribute__((address_space(3))) void*)l, 16, 0, 0);
}

// ---------------------------------------------------------------------------
__global__ void init_k(int* flags) { flags[0] = 0; flags[1] = LL; }

__global__ void write_depth_k(float* out, const int* flags) { out[0] = (float)flags[1]; }

// ---------------------------------------------------------------------------
// All 6 weight transposes of one layer in a single launch (12288 blocks).
// fp32 [R][C] -> bf16 [C][R].
__global__ __launch_bounds__(256) void transpose_all(
    const float* __restrict__ Wq, const float* __restrict__ Wk,
    const float* __restrict__ Wv, const float* __restrict__ Wo,
    const float* __restrict__ W1f, const float* __restrict__ W2f,
    short* __restrict__ wqkv, short* __restrict__ wto,
    short* __restrict__ wt1, short* __restrict__ wt2,
    const int* __restrict__ done)
{
    if (*done) return;
    const int bid = blockIdx.x;
    const float* in; short* out; int R, C, bx, by;
    if (bid < 3072) {                       // q,k,v -> wqkv[3072][1024]
        const int wsel = bid >> 10, local = bid & 1023;
        in = wsel == 0 ? Wq : (wsel == 1 ? Wk : Wv);
        out = wqkv + (size_t)wsel * DD * DD;
        R = DD; C = DD; bx = local & 31; by = local >> 5;
    } else if (bid < 4096) {                // o
        const int local = bid - 3072;
        in = Wo; out = wto; R = DD; C = DD; bx = local & 31; by = local >> 5;
    } else if (bid < 8192) {                // W1 [1024][4096] -> [4096][1024]
        const int local = bid - 4096;
        in = W1f; out = wt1; R = DD; C = FF; bx = local & 127; by = local >> 7;
    } else {                                // W2 [4096][1024] -> [1024][4096]
        const int local = bid - 8192;
        in = W2f; out = wt2; R = FF; C = DD; bx = local & 31; by = local >> 5;
    }
    __shared__ float t[32][33];
    const int tx = threadIdx.x & 31, ty = threadIdx.x >> 5;  // 32x8
    const int r0 = by * 32, c0 = bx * 32;
#pragma unroll
    for (int j = 0; j < 32; j += 8)
        t[ty + j][tx] = in[(size_t)(r0 + ty + j) * C + c0 + tx];
    __syncthreads();
#pragma unroll
    for (int j = 0; j < 32; j += 8)
        out[(size_t)(c0 + ty + j) * R + r0 + tx] = f2bf(t[tx][ty + j]);
}

// ---------------------------------------------------------------------------
// LayerNorm over D=1024; fp32 in -> bf16 out. One block per row, 256 threads.
__global__ __launch_bounds__(256) void layernorm_k(
    const float* __restrict__ x, const float* __restrict__ g, const float* __restrict__ b,
    short* __restrict__ out, const int* __restrict__ done)
{
    if (*done) return;
    const int row = blockIdx.x, tid = threadIdx.x;
    const f32x4 v = *(const f32x4*)(x + (size_t)row * DD + tid * 4);
    float s  = v[0] + v[1] + v[2] + v[3];
    float sq = v[0]*v[0] + v[1]*v[1] + v[2]*v[2] + v[3]*v[3];
#pragma unroll
    for (int m = 1; m < 64; m <<= 1) { s += __shfl_xor(s, m, 64); sq += __shfl_xor(sq, m, 64); }
    __shared__ float red[8];
    if ((tid & 63) == 0) { red[tid >> 6] = s; red[4 + (tid >> 6)] = sq; }
    __syncthreads();
    s  = red[0] + red[1] + red[2] + red[3];
    sq = red[4] + red[5] + red[6] + red[7];
    const float mean = s * (1.f / DD);
    const float rstd = rsqrtf(sq * (1.f / DD) - mean * mean + 1e-5f);
    const f32x4 gg = *(const f32x4*)(g + tid * 4);
    const f32x4 bb = *(const f32x4*)(b + tid * 4);
    s16x4 o;
#pragma unroll
    for (int j = 0; j < 4; ++j) o[j] = f2bf((v[j] - mean) * rstd * gg[j] + bb[j]);
    *(s16x4*)(out + (size_t)row * DD + tid * 4) = o;
}

// ---------------------------------------------------------------------------
// GEMM: C[M][N] = A[M][K](bf16) @ Bt[N][K]^T(bf16) + bias
// EPI 0: bf16 out (Cq); 1: bf16 relu out (Cq); 2: fp32 in-place residual (Cf);
// EPI 4: fused QKV (N=3072): cols 0-1023 -> Cq bf16 [M][1024], 1024-2047 -> Ck,
//        2048-3071 -> Cv transposed head-major V^T [bh][64][2048].
// 128x128 tile, BK=32, 4 waves (2x2), 16x16x32 bf16 MFMA, 4x4 frags/wave.
// Staging via global_load_lds width=16 into LINEAR [128][32] LDS (m97 structure).
template<int EPI>
__global__ __launch_bounds__(256) void gemm_bt(
    const short* __restrict__ A, const short* __restrict__ Bt,
    const float* __restrict__ b0, const float* __restrict__ b1, const float* __restrict__ b2,
    short* __restrict__ Cq, short* __restrict__ Ck, short* __restrict__ Cv,
    float* __restrict__ Cf,
    int M, int N, int K, const int* __restrict__ done)
{
    if (*done) return;
    __shared__ __align__(16) short As[128 * 32];   // linear, row-major [128][32]
    __shared__ __align__(16) short Bs[128 * 32];
    const int tid = threadIdx.x;
    const int lane = tid & 63;
    const int wave = tid >> 6;
    const int wr = (wave >> 1) * 64, wc = (wave & 1) * 64;
    const int row0 = blockIdx.y * 128, col0 = blockIdx.x * 128;
    // chunk c in [0,512): row=c>>2, k-chunk=(c&3)*8 shorts. 2 chunks/thread.
    const int r0c = tid >> 2,        k0c = (tid & 3) * 8;
    const int r1c = (256 + tid) >> 2, k1c = (tid & 3) * 8;
    short* dstA0 = As + (size_t)(wave * 64) * 8;
    short* dstA1 = As + (size_t)(256 + wave * 64) * 8;
    short* dstB0 = Bs + (size_t)(wave * 64) * 8;
    short* dstB1 = Bs + (size_t)(256 + wave * 64) * 8;
    f32x4 acc[4][4] = {};
    for (int kt = 0; kt < K; kt += 32) {
        gl_lds16(A  + (size_t)(row0 + r0c) * K + kt + k0c, dstA0);
        gl_lds16(A  + (size_t)(row0 + r1c) * K + kt + k1c, dstA1);
        gl_lds16(Bt + (size_t)(col0 + r0c) * K + kt + k0c, dstB0);
        gl_lds16(Bt + (size_t)(col0 + r1c) * K + kt + k1c, dstB1);
        __syncthreads();
        s16x8 af[4], bfr[4];
#pragma unroll
        for (int m = 0; m < 4; ++m)
            af[m] = *(const s16x8*)&As[(wr + m * 16 + (lane & 15)) * 32 + (lane >> 4) * 8];
#pragma unroll
        for (int n = 0; n < 4; ++n)
            bfr[n] = *(const s16x8*)&Bs[(wc + n * 16 + (lane & 15)) * 32 + (lane >> 4) * 8];
#pragma unroll
        for (int m = 0; m < 4; ++m)
#pragma unroll
            for (int n = 0; n < 4; ++n)
                acc[m][n] = __builtin_amdgcn_mfma_f32_16x16x32_bf16(af[m], bfr[n], acc[m][n], 0, 0, 0);
        __syncthreads();
    }
    const int sel = col0 >> 10;  // uniform per block (EPI 4)
    const float* bp = (EPI == 4) ? (sel == 0 ? b0 : (sel == 1 ? b1 : b2)) : b0;
#pragma unroll
    for (int m = 0; m < 4; ++m) {
        const int row = row0 + wr + m * 16 + (lane >> 4) * 4;
#pragma unroll
        for (int n = 0; n < 4; ++n) {
            const int col = col0 + wc + n * 16 + (lane & 15);
            if (EPI == 4) {
                const int colq = col & 1023;
                const float bcol = bp[colq];
                if (sel < 2) {
                    short* dst = sel == 0 ? Cq : Ck;
#pragma unroll
                    for (int i = 0; i < 4; ++i)
                        dst[(size_t)(row + i) * DD + colq] = f2bf(acc[m][n][i] + bcol);
                } else {
                    // V^T: Cv[(bh*64+d)*2048 + s], 4 consecutive s per store
                    const int bh = (row >> 11) * HH + (colq >> 6);
                    const int d = colq & 63, s = row & 2047;
                    s16x4 o;
#pragma unroll
                    for (int i = 0; i < 4; ++i) o[i] = f2bf(acc[m][n][i] + bcol);
                    *(s16x4*)(Cv + ((size_t)bh * 64 + d) * SS + s) = o;
                }
            } else {
                const float bcol = bp[col];
#pragma unroll
                for (int i = 0; i < 4; ++i) {
                    const float v = acc[m][n][i] + bcol;
                    const size_t idx = (size_t)(row + i) * N + col;
                    if (EPI == 0)      Cq[idx] = f2bf(v);
                    else if (EPI == 1) Cq[idx] = f2bf(v > 0.f ? v : 0.f);
                    else               Cf[idx] = Cf[idx] + v;
                }
            }
        }
    }
}

// ---------------------------------------------------------------------------
// Flash attention, causal. Q/K/O: bf16 [B*S][D] row-major; V pre-transposed
// vt[bh][64 d][2048 s]. Block: 4 waves; 64-row q-tiles fold-paired {t, 31-t}
// (33 uniform KV iterations). Wave = 16 q-rows. Rowsum via MFMA-ones column.
__global__ __launch_bounds__(256) void attn_k(
    const short* __restrict__ Q, const short* __restrict__ Kk, const short* __restrict__ Vt_g,
    short* __restrict__ O, const int* __restrict__ done)
{
    if (*done) return;
    __shared__ __align__(16) short Ks[64][72];    // K tile [kv][d], padded
    __shared__ __align__(16) short Vs[64][72];    // V^T tile [d][kv], padded
    __shared__ __align__(16) short Pl[4][16][72]; // per-wave P [q][kv], padded
    const int tid = threadIdx.x, lane = tid & 63, wave = tid >> 6;
    const int bh = blockIdx.y, b = bh >> 4, h = bh & 15;
    const size_t headoff = (size_t)b * SS * DD + h * HDIM;
    const size_t vhead = (size_t)bh * 64 * SS;
    const float sc = 0.125f * 1.44269504089f;  // scale * log2(e)
    const int r2 = tid >> 3, k2 = (tid & 7) * 8;   // K staging rows 0..31 (+32)
    const int rvA = tid >> 3, cvA = (tid & 7) * 8; // V^T staging rows 0..31
    const int rvB = 32 + rvA;                      // rows 32..63
    s16x8 ones;
#pragma unroll
    for (int j = 0; j < 8; ++j) ones[j] = (short)0x3F80;  // bf16 1.0
    for (int half = 0; half < 2; ++half) {
        const int qtile = half ? (31 - blockIdx.x) : blockIdx.x;  // x in [0,16)
        const int qblock = qtile * 64;
        const int q0 = qblock + wave * 16;
        // Q fragments (held in regs for this half)
        s16x8 qf[2];
#pragma unroll
        for (int d0 = 0; d0 < 2; ++d0)
            qf[d0] = *(const s16x8*)(Q + headoff +
                (size_t)(q0 + (lane & 15)) * DD + d0 * 32 + (lane >> 4) * 8);
        f32x4 oacc[4] = {};
        f32x4 ol = {};                 // ones-column accumulator = row sums
        float mrow[4];
#pragma unroll
        for (int i = 0; i < 4; ++i) mrow[i] = -__builtin_inff();
        for (int jb = 0; jb <= qblock; jb += 64) {
            *(s16x8*)&Ks[r2][k2]      = *(const s16x8*)(Kk + headoff + (size_t)(jb + r2) * DD + k2);
            *(s16x8*)&Ks[r2 + 32][k2] = *(const s16x8*)(Kk + headoff + (size_t)(jb + r2 + 32) * DD + k2);
            *(s16x8*)&Vs[rvA][cvA]    = *(const s16x8*)(Vt_g + vhead + (size_t)rvA * SS + jb + cvA);
            *(s16x8*)&Vs[rvB][cvA]    = *(const s16x8*)(Vt_g + vhead + (size_t)rvB * SS + jb + cvA);
            __syncthreads();
            // QK^T: S[16 q][64 kv]
            f32x4 sf[4] = {};
#pragma unroll
            for (int n = 0; n < 4; ++n)
#pragma unroll
                for (int d0 = 0; d0 < 2; ++d0) {
                    const s16x8 kf = *(const s16x8*)&Ks[n * 16 + (lane & 15)][d0 * 32 + (lane >> 4) * 8];
                    sf[n] = __builtin_amdgcn_mfma_f32_16x16x32_bf16(qf[d0], kf, sf[n], 0, 0, 0);
                }
            const bool needmask = (jb + 63 > q0);
            float tmax[4] = {-__builtin_inff(), -__builtin_inff(), -__builtin_inff(), -__builtin_inff()};
#pragma unroll
            for (int n = 0; n < 4; ++n)
#pragma unroll
                for (int i = 0; i < 4; ++i) {
                    float s = sf[n][i] * sc;
                    if (needmask) {
                        const int kv = jb + n * 16 + (lane & 15);
                        const int qr = q0 + (lane >> 4) * 4 + i;
                        if (kv > qr) s = -1e30f;
                    }
                    sf[n][i] = s;
                    tmax[i] = fmaxf(tmax[i], s);
                }
#pragma unroll
            for (int i = 0; i < 4; ++i) {
#pragma unroll
                for (int mk = 1; mk < 16; mk <<= 1)
                    tmax[i] = fmaxf(tmax[i], __shfl_xor(tmax[i], mk, 64));
                const float mnew = fmaxf(mrow[i], tmax[i]);
                const float alpha = exp2f(mrow[i] - mnew);
                mrow[i] = mnew;
                ol[i] *= alpha;
#pragma unroll
                for (int df = 0; df < 4; ++df) oacc[df][i] *= alpha;
            }
#pragma unroll
            for (int n = 0; n < 4; ++n)
#pragma unroll
                for (int i = 0; i < 4; ++i) {
                    const float p = exp2f(sf[n][i] - mrow[i]);
                    Pl[wave][(lane >> 4) * 4 + i][n * 16 + (lane & 15)] = f2bf(p);
                }
            // PV + ones-column rowsum (wave-private Pl; compiler inserts ds waits)
#pragma unroll
            for (int ks = 0; ks < 2; ++ks) {
                const s16x8 pa = *(const s16x8*)&Pl[wave][lane & 15][ks * 32 + (lane >> 4) * 8];
                ol = __builtin_amdgcn_mfma_f32_16x16x32_bf16(pa, ones, ol, 0, 0, 0);
#pragma unroll
                for (int df = 0; df < 4; ++df) {
                    const s16x8 vbf = *(const s16x8*)&Vs[df * 16 + (lane & 15)][ks * 32 + (lane >> 4) * 8];
                    oacc[df] = __builtin_amdgcn_mfma_f32_16x16x32_bf16(pa, vbf, oacc[df], 0, 0, 0);
                }
            }
            __syncthreads();
        }
#pragma unroll
        for (int i = 0; i < 4; ++i) {
            const int qr = q0 + (lane >> 4) * 4 + i;
            const float inv = 1.f / ol[i];
#pragma unroll
            for (int df = 0; df < 4; ++df)
                O[headoff + (size_t)qr * DD + df * 16 + (lane & 15)] = f2bf(oacc[df][i] * inv);
        }
    }
}

// ---------------------------------------------------------------------------
// Confidence path: column sums of x over seq, then probe + sigmoid + mean.
__global__ void zero_colsum(float* cs, const int* done) {
    if (*done) return;
    cs[blockIdx.x * 256 + threadIdx.x] = 0.f;
}

__global__ __launch_bounds__(256) void colsum_k(
    const float* __restrict__ x, float* __restrict__ cs, const int* __restrict__ done)
{
    if (*done) return;
    const int d = (blockIdx.x & 3) * 256 + threadIdx.x;
    const int b = blockIdx.x >> 2;
    const int s0 = blockIdx.y * 128;
    float s = 0.f;
    for (int i = 0; i < 128; ++i) s += x[(size_t)(b * SS + s0 + i) * DD + d];
    atomicAdd(&cs[b * DD + d], s);
}

__global__ __launch_bounds__(256) void conf_k(
    const float* __restrict__ colsum, const float* __restrict__ cW, const float* __restrict__ cb,
    int layer, int* __restrict__ flags)
{
    if (flags[0]) return;
    const int tid = threadIdx.x;
    __shared__ float red[4][4];
    float dot[4];
#pragma unroll
    for (int b = 0; b < 4; ++b) {
        float p = 0.f;
        for (int d = tid; d < DD; d += 256) p += colsum[b * DD + d] * cW[d];
#pragma unroll
        for (int m = 1; m < 64; m <<= 1) p += __shfl_xor(p, m, 64);
        dot[b] = p;
    }
    if ((tid & 63) == 0) {
#pragma unroll
        for (int b = 0; b < 4; ++b) red[b][tid >> 6] = dot[b];
    }
    __syncthreads();
    if (tid == 0) {
        float conf = 0.f;
#pragma unroll
        for (int b = 0; b < 4; ++b) {
            const float db = (red[b][0] + red[b][1] + red[b][2] + red[b][3]) * (1.f / SS) + cb[0];
            conf += 1.f / (1.f + expf(-db));
        }
        conf *= 0.25f;
        if (layer >= 1 && conf > 0.93f) { flags[0] = 1; flags[1] = layer + 1; }
    }
}

// ---------------------------------------------------------------------------
extern "C" void kernel_launch(void* const* d_in, const int* in_sizes, int n_in,
                              void* d_out, int out_size, void* d_ws, size_t ws_size,
                              hipStream_t stream)
{
    const float* x_in = (const float*)d_in[0];
    const float* Wq  = (const float*)d_in[1];
    const float* bq  = (const float*)d_in[2];
    const float* Wk  = (const float*)d_in[3];
    const float* bk  = (const float*)d_in[4];
    const float* Wv  = (const float*)d_in[5];
    const float* bv  = (const float*)d_in[6];
    const float* Wo  = (const float*)d_in[7];
    const float* bo  = (const float*)d_in[8];
    const float* W1  = (const float*)d_in[9];
    const float* b1  = (const float*)d_in[10];
    const float* W2  = (const float*)d_in[11];
    const float* b2  = (const float*)d_in[12];
    const float* g1  = (const float*)d_in[13];
    const float* be1 = (const float*)d_in[14];
    const float* g2  = (const float*)d_in[15];
    const float* be2 = (const float*)d_in[16];
    const float* cW  = (const float*)d_in[17];
    const float* cb  = (const float*)d_in[18];

    char* ws = (char*)d_ws;
    size_t off = 0;
    auto alloc = [&](size_t bytes) -> char* {
        char* p = ws + off;
        off = (off + bytes + 255) & ~(size_t)255;
        return p;
    };
    int*   flags  = (int*)  alloc(256);
    float* colsum = (float*)alloc((size_t)BB * DD * 4);
    short* xn     = (short*)alloc((size_t)MM * DD * 2);
    short* qb     = (short*)alloc((size_t)MM * DD * 2);
    short* kb     = (short*)alloc((size_t)MM * DD * 2);
    short* vt     = (short*)alloc((size_t)MM * DD * 2);  // V^T [bh][64][2048]
    short* obuf   = (short*)alloc((size_t)MM * DD * 2);
    short* hb     = qb;  // FFN hidden [MM][FF] bf16 overlaps q/k/vt/o (dead by then)
    short* wqkv   = (short*)alloc((size_t)3 * DD * DD * 2);  // [3072][1024]
    short* wto    = (short*)alloc((size_t)DD * DD * 2);
    short* wt1    = (short*)alloc((size_t)DD * FF * 2);
    short* wt2    = (short*)alloc((size_t)DD * FF * 2);
    (void)ws_size; (void)in_sizes; (void)n_in; (void)out_size;

    // fp32 residual stream lives directly in d_out (out layout: [MM*DD floats][depth])
    float* x = (float*)d_out;

    hipMemcpyAsync(x, x_in, (size_t)MM * DD * 4, hipMemcpyDeviceToDevice, stream);
    init_k<<<1, 1, 0, stream>>>(flags);
    const int* done = flags;

    for (int l = 0; l < LL; ++l) {
        const size_t wdd = (size_t)l * DD * DD;
        const size_t wdf = (size_t)l * DD * FF;
        transpose_all<<<12288, 256, 0, stream>>>(Wq + wdd, Wk + wdd, Wv + wdd, Wo + wdd,
                                                 W1 + wdf, W2 + wdf,
                                                 wqkv, wto, wt1, wt2, done);

        layernorm_k<<<MM, 256, 0, stream>>>(x, g1 + l * DD, be1 + l * DD, xn, done);
        gemm_bt<4><<<dim3(3 * DD / 128, MM / 128), 256, 0, stream>>>(
            xn, wqkv, bq + l * DD, bk + l * DD, bv + l * DD,
            qb, kb, vt, nullptr, MM, 3 * DD, DD, done);
        attn_k<<<dim3(16, BB * HH), 256, 0, stream>>>(qb, kb, vt, obuf, done);
        gemm_bt<2><<<dim3(DD / 128, MM / 128), 256, 0, stream>>>(
            obuf, wto, bo + l * DD, nullptr, nullptr,
            nullptr, nullptr, nullptr, x, MM, DD, DD, done);
        layernorm_k<<<MM, 256, 0, stream>>>(x, g2 + l * DD, be2 + l * DD, xn, done);
        gemm_bt<1><<<dim3(FF / 128, MM / 128), 256, 0, stream>>>(
            xn, wt1, b1 + (size_t)l * FF, nullptr, nullptr,
            hb, nullptr, nullptr, nullptr, MM, FF, DD, done);
        gemm_bt<2><<<dim3(DD / 128, MM / 128), 256, 0, stream>>>(
            hb, wt2, b2 + l * DD, nullptr, nullptr,
            nullptr, nullptr, nullptr, x, MM, DD, FF, done);

        zero_colsum<<<16, 256, 0, stream>>>(colsum, done);
        colsum_k<<<dim3(16, 16), 256, 0, stream>>>(x, colsum, done);
        conf_k<<<1, 256, 0, stream>>>(colsum, cW + l * DD, cb + l, l, flags);
    }

    write_depth_k<<<1, 1, 0, stream>>>((float*)d_out + (size_t)MM * DD, flags);
}